// Round 2
// baseline (309.310 us; speedup 1.0000x reference)
//
#include <hip/hip_runtime.h>
#include <stdint.h>

#define BATCH 128
#define LCOUNT 196
#define LP1 197
#define DIM 1024

typedef __bf16 bf16x8 __attribute__((ext_vector_type(8)));
typedef float f32x4 __attribute__((ext_vector_type(4)));

__device__ inline float bflo(uint32_t u){ union{uint32_t i; float f;} x; x.i = u << 16; return x.f; }
__device__ inline float bfhi(uint32_t u){ union{uint32_t i; float f;} x; x.i = u & 0xffff0000u; return x.f; }
__device__ inline float bf2f(uint16_t h){ union{uint32_t i; float f;} x; x.i = ((uint32_t)h) << 16; return x.f; }
__device__ inline uint16_t f2bf(float f){
  union{float f; uint32_t u;} x; x.f = f;
  uint32_t r = x.u + 0x7fffu + ((x.u >> 16) & 1u);
  return (uint16_t)(r >> 16);
}
__device__ inline float tanh_fast(float x){
  float e = __expf(2.0f * x);
  return 1.0f - 2.0f / (e + 1.0f);
}
__device__ inline void unpack8(uint4 u, float* x){
  x[0]=bflo(u.x); x[1]=bfhi(u.x); x[2]=bflo(u.y); x[3]=bfhi(u.y);
  x[4]=bflo(u.z); x[5]=bfhi(u.z); x[6]=bflo(u.w); x[7]=bfhi(u.w);
}

// ---------------- dtype detect: flag=1 if buffers are fp32, 0 if bf16 -------
// W_fr ~ uniform(+-1/32). If bf16: every u16 decodes to |x|<=0.03125.
// If fp32: even u16s are mantissa halves -> random exponents, huge/NaN values.
__global__ __launch_bounds__(256) void detect_k(const uint16_t* __restrict__ w,
                                                int* __restrict__ flag) {
  int t = threadIdx.x;
  if (t == 0) *flag = 0;
  __syncthreads();
  int bad = 0;
  #pragma unroll
  for (int i = 0; i < 16; ++i) {
    float v = bf2f(w[(t * 16 + i) * 2]);          // even positions
    if (!(fabsf(v) <= 1000.0f)) bad = 1;          // catches huge AND NaN
  }
  if (bad) *flag = 1;
}

// ---------------- normalize big tensors -> bf16 ------------------------------
struct Cvt4 { const void* src; uint16_t* dst; int n4; };
struct CvtMainArgs { Cvt4 d[7]; const int* flag; };

__global__ __launch_bounds__(256) void cvt_main_k(CvtMainArgs a) {
  int g = blockIdx.x * 256 + threadIdx.x;
  int base = 0, i = 0;
  #pragma unroll
  for (i = 0; i < 7; ++i) { if (g < base + a.d[i].n4) break; base += a.d[i].n4; }
  if (i >= 7) return;
  int e = (g - base) * 4;
  if (*a.flag) {
    float4 v = *((const float4*)a.d[i].src + (e >> 2));
    uint2 o;
    o.x = (uint32_t)f2bf(v.x) | ((uint32_t)f2bf(v.y) << 16);
    o.y = (uint32_t)f2bf(v.z) | ((uint32_t)f2bf(v.w) << 16);
    *(uint2*)(a.d[i].dst + e) = o;
  } else {
    uint2 v = *((const uint2*)a.d[i].src + (e >> 2));
    *(uint2*)(a.d[i].dst + e) = v;
  }
}

// ---------------- normalize small tensors -> fp32 ----------------------------
struct CvtS { const void* src; float* dst; int n; };
struct CvtSmallArgs { CvtS d[7]; const int* flag; };

__global__ __launch_bounds__(256) void cvt_small_k(CvtSmallArgs a) {
  CvtS d = a.d[blockIdx.x];
  bool f = (*a.flag != 0);
  for (int i = threadIdx.x; i < d.n; i += 256)
    d.dst[i] = f ? ((const float*)d.src)[i] : bf2f(((const uint16_t*)d.src)[i]);
}

// ---------------- GEMM: C[m,n] = act(sum_k A[m,k]*W[n,k] + bias[n]) ----------
struct GemmArgs {
  const uint16_t* A;     // [128,1024] bf16 (normalized)
  const uint16_t* W;     // [1024,1024] bf16 (normalized, row-major [N,K])
  const float*    bias;  // [1024] fp32 (normalized)
  uint16_t* out_bf;      // bf16 out or null
  float*    out_f;       // fp32 out or null
  int act;               // 0 none, 1 relu, 2 tanh
  const int* oflag;      // if non-null: dual-mode out (fp32 if *oflag else bf16)
};

__global__ __launch_bounds__(256) void gemm_k(GemmArgs g0, GemmArgs g1) {
  GemmArgs g = (blockIdx.z == 0) ? g0 : g1;
  const int K = DIM, N = DIM;
  int wave = threadIdx.x >> 6;
  int lane = threadIdx.x & 63;
  int r    = lane & 15;
  int quad = lane >> 4;
  int m0 = blockIdx.x * 32 + (wave >> 1) * 16;
  int n0 = blockIdx.y * 32 + (wave & 1) * 16;
  const uint16_t* Ap = g.A + (size_t)(m0 + r) * K + quad * 8;
  const uint16_t* Wp = g.W + (size_t)(n0 + r) * K + quad * 8;
  f32x4 acc = {0.f, 0.f, 0.f, 0.f};
  #pragma unroll 8
  for (int k = 0; k < K; k += 32) {
    bf16x8 a = *(const bf16x8*)(Ap + k);
    bf16x8 b = *(const bf16x8*)(Wp + k);
    acc = __builtin_amdgcn_mfma_f32_16x16x32_bf16(a, b, acc, 0, 0, 0);
  }
  int col = n0 + r;
  float bv = g.bias[col];
  #pragma unroll
  for (int i = 0; i < 4; ++i) {
    int row = m0 + quad * 4 + i;
    float v = acc[i] + bv;
    if (g.act == 1) v = fmaxf(v, 0.f);
    else if (g.act == 2) v = tanhf(v);
    size_t idx = (size_t)row * N + col;
    if (g.oflag) {
      if (*g.oflag) g.out_f[idx] = v; else g.out_bf[idx] = f2bf(v);
    } else {
      if (g.out_bf) g.out_bf[idx] = f2bf(v);
      if (g.out_f)  g.out_f[idx]  = v;
    }
  }
}

// ---------------- scores[b,l] = dot(tanh(embed_row + hoe[b]), Wa) + ba -------
__global__ __launch_bounds__(256) void scores_k(
    const int*   __restrict__ flag,
    const void*  __restrict__ cfe,   // [B,196,1024] bf16 or fp32 (raw input)
    const float* __restrict__ fre,   // [B,1024] fp32 (ws)
    const float* __restrict__ hoe,   // [B,1024] fp32 (ws)
    const float* __restrict__ Wa,    // [1024] fp32 (ws)
    const float* __restrict__ ba,    // [1] fp32 (ws)
    float* __restrict__ scores)      // [B,197]
{
  int row  = blockIdx.x * 4 + (threadIdx.x >> 6);
  int lane = threadIdx.x & 63;
  if (row >= BATCH * LP1) return;
  int b = row / LP1;
  int l = row - b * LP1;
  int d0 = lane * 16;
  bool f32m = (*flag != 0);

  float x[16];
  if (l == 0) {
    const float4* fp = (const float4*)(fre + b * DIM + d0);
    #pragma unroll
    for (int q = 0; q < 4; ++q) {
      float4 f = fp[q];
      x[q*4+0]=f.x; x[q*4+1]=f.y; x[q*4+2]=f.z; x[q*4+3]=f.w;
    }
  } else if (f32m) {
    const float4* p = (const float4*)((const float*)cfe +
                       ((size_t)b * LCOUNT + (l - 1)) * DIM + d0);
    #pragma unroll
    for (int q = 0; q < 4; ++q) {
      float4 f = p[q];
      x[q*4+0]=f.x; x[q*4+1]=f.y; x[q*4+2]=f.z; x[q*4+3]=f.w;
    }
  } else {
    const uint4* p = (const uint4*)((const uint16_t*)cfe +
                      ((size_t)b * LCOUNT + (l - 1)) * DIM + d0);
    uint4 u0 = p[0], u1 = p[1];
    unpack8(u0, x); unpack8(u1, x + 8);
  }
  const float4* wp = (const float4*)(Wa + d0);
  const float4* hp = (const float4*)(hoe + b * DIM + d0);
  float sum = 0.f;
  #pragma unroll
  for (int q = 0; q < 4; ++q) {
    float4 h = hp[q];
    float4 w = wp[q];
    sum += tanh_fast(x[q*4+0] + h.x) * w.x;
    sum += tanh_fast(x[q*4+1] + h.y) * w.y;
    sum += tanh_fast(x[q*4+2] + h.z) * w.z;
    sum += tanh_fast(x[q*4+3] + h.w) * w.w;
  }
  #pragma unroll
  for (int off = 32; off > 0; off >>= 1) sum += __shfl_down(sum, off);
  if (lane == 0) scores[row] = sum + ba[0];
}

// ---------------- softmax over 197 per batch --------------------------------
__global__ __launch_bounds__(256) void softmax_k(const float* __restrict__ scores,
                                                 float* __restrict__ PI) {
  int b = blockIdx.x, t = threadIdx.x;
  int lane = t & 63, wave = t >> 6;
  float v = (t < LP1) ? scores[b * LP1 + t] : -1e30f;
  float m = v;
  #pragma unroll
  for (int off = 32; off > 0; off >>= 1) m = fmaxf(m, __shfl_down(m, off));
  __shared__ float red[4];
  if (lane == 0) red[wave] = m;
  __syncthreads();
  m = fmaxf(fmaxf(red[0], red[1]), fmaxf(red[2], red[3]));
  float e = (t < LP1) ? expf(v - m) : 0.f;
  float s = e;
  #pragma unroll
  for (int off = 32; off > 0; off >>= 1) s += __shfl_down(s, off);
  __syncthreads();
  if (lane == 0) red[wave] = s;
  __syncthreads();
  s = red[0] + red[1] + red[2] + red[3];
  if (t < LP1) PI[b * LP1 + t] = e / s;
}

// ---------------- visAtt + ho -> attout (bf16) ------------------------------
__global__ __launch_bounds__(256) void visatt_k(
    const int*      __restrict__ flag,
    const void*     __restrict__ cf,    // [B,196,1024] bf16 or fp32 (raw input)
    const uint16_t* __restrict__ frb,   // [B,1024] bf16 (ws)
    const float*    __restrict__ hof,   // [B,1024] fp32 (ws)
    const float*    __restrict__ PI,    // [B,197]
    uint16_t* __restrict__ attout)      // [B,1024] bf16
{
  int b  = blockIdx.x;
  int d0 = threadIdx.x * 4;
  __shared__ float pis[LP1];
  for (int i = threadIdx.x; i < LP1; i += 256) pis[i] = PI[b * LP1 + i];
  __syncthreads();
  float a0, a1, a2, a3;
  {
    uint2 u = *(const uint2*)(frb + b * DIM + d0);
    float p = pis[0];
    a0 = p * bflo(u.x); a1 = p * bfhi(u.x); a2 = p * bflo(u.y); a3 = p * bfhi(u.y);
  }
  if (*flag) {
    const float* base = (const float*)cf + (size_t)b * LCOUNT * DIM + d0;
    #pragma unroll 4
    for (int l = 0; l < LCOUNT; ++l) {
      float4 v = *(const float4*)(base + (size_t)l * DIM);
      float p = pis[l + 1];
      a0 += p * v.x; a1 += p * v.y; a2 += p * v.z; a3 += p * v.w;
    }
  } else {
    const uint16_t* base = (const uint16_t*)cf + (size_t)b * LCOUNT * DIM + d0;
    #pragma unroll 4
    for (int l = 0; l < LCOUNT; ++l) {
      uint2 u = *(const uint2*)(base + (size_t)l * DIM);
      float p = pis[l + 1];
      a0 += p * bflo(u.x); a1 += p * bfhi(u.x);
      a2 += p * bflo(u.y); a3 += p * bfhi(u.y);
    }
  }
  const float* hb = hof + b * DIM + d0;
  a0 += hb[0]; a1 += hb[1]; a2 += hb[2]; a3 += hb[3];
  uint2 o;
  o.x = (uint32_t)f2bf(a0) | ((uint32_t)f2bf(a1) << 16);
  o.y = (uint32_t)f2bf(a2) | ((uint32_t)f2bf(a3) << 16);
  *(uint2*)(attout + b * DIM + d0) = o;
}

// ---------------- launch -----------------------------------------------------
extern "C" void kernel_launch(void* const* d_in, const int* in_sizes, int n_in,
                              void* d_out, int out_size, void* d_ws, size_t ws_size,
                              hipStream_t stream) {
  const void* h_out       = d_in[0];
  const void* fake_region = d_in[1];
  const void* conv_feat   = d_in[2];
  const void* conv_feat_e = d_in[3];
  const void* W_fr  = d_in[4];
  const void* b_fr  = d_in[5];
  const void* W_fre = d_in[6];
  const void* b_fre = d_in[7];
  const void* W_ho  = d_in[8];
  const void* b_ho  = d_in[9];
  const void* W_hoe = d_in[10];
  const void* b_hoe = d_in[11];
  const void* W_a   = d_in[12];
  const void* b_a   = d_in[13];
  const void* W_h   = d_in[14];
  const void* b_h   = d_in[15];

  char* ws = (char*)d_ws;
  int*      flag    = (int*)     (ws + 0);
  uint16_t* hout_bf = (uint16_t*)(ws + 256);
  uint16_t* freg_bf = (uint16_t*)(ws + 262400);
  uint16_t* Wfr_bf  = (uint16_t*)(ws + 524544);
  uint16_t* Wfre_bf = (uint16_t*)(ws + 2621696);
  uint16_t* Who_bf  = (uint16_t*)(ws + 4718848);
  uint16_t* Whoe_bf = (uint16_t*)(ws + 6816000);
  uint16_t* Wh_bf   = (uint16_t*)(ws + 8913152);
  float*    Wa_f    = (float*)   (ws + 11010304);
  float*    bfr_f   = (float*)   (ws + 11014400);
  float*    bfre_f  = (float*)   (ws + 11018496);
  float*    bho_f   = (float*)   (ws + 11022592);
  float*    bhoe_f  = (float*)   (ws + 11026688);
  float*    bh_f    = (float*)   (ws + 11030784);
  float*    ba_f    = (float*)   (ws + 11034880);
  uint16_t* fr_bf   = (uint16_t*)(ws + 11035136);
  uint16_t* ho_bf   = (uint16_t*)(ws + 11297280);
  float*    ho_f    = (float*)   (ws + 11559424);
  float*    fre_f   = (float*)   (ws + 12083712);
  float*    hoe_f   = (float*)   (ws + 12608000);
  float*    scores  = (float*)   (ws + 13132288);
  float*    PI      = (float*)   (ws + 13234688);
  uint16_t* attout  = (uint16_t*)(ws + 13337088);

  dim3 blk(256);

  // 0: dtype probe on W_fr
  detect_k<<<dim3(1), blk, 0, stream>>>((const uint16_t*)W_fr, flag);

  // 1: normalize big tensors -> bf16 (activations + 5 weight matrices)
  CvtMainArgs cm;
  cm.d[0] = { h_out,       hout_bf, 131072/4 };
  cm.d[1] = { fake_region, freg_bf, 131072/4 };
  cm.d[2] = { W_fr,  Wfr_bf,  1048576/4 };
  cm.d[3] = { W_fre, Wfre_bf, 1048576/4 };
  cm.d[4] = { W_ho,  Who_bf,  1048576/4 };
  cm.d[5] = { W_hoe, Whoe_bf, 1048576/4 };
  cm.d[6] = { W_h,   Wh_bf,   1048576/4 };
  cm.flag = flag;
  cvt_main_k<<<dim3(5376), blk, 0, stream>>>(cm);   // 1376256 groups of 4

  // 2: normalize small tensors -> fp32 (biases + W_a + b_a)
  CvtSmallArgs cs;
  cs.d[0] = { b_fr,  bfr_f,  1024 };
  cs.d[1] = { b_fre, bfre_f, 1024 };
  cs.d[2] = { b_ho,  bho_f,  1024 };
  cs.d[3] = { b_hoe, bhoe_f, 1024 };
  cs.d[4] = { b_h,   bh_f,   1024 };
  cs.d[5] = { W_a,   Wa_f,   1024 };
  cs.d[6] = { b_a,   ba_f,   1 };
  cs.flag = flag;
  cvt_small_k<<<dim3(7), blk, 0, stream>>>(cs);

  // 3: fr = relu(freg@W_fr^T+b), ho = tanh(h_out@W_ho^T+b)
  GemmArgs ga{freg_bf, Wfr_bf, bfr_f, fr_bf, nullptr, 1, nullptr};
  GemmArgs gb{hout_bf, Who_bf, bho_f, ho_bf, ho_f,    2, nullptr};
  gemm_k<<<dim3(4, 32, 2), blk, 0, stream>>>(ga, gb);

  // 4: fr_e = fr@W_fre^T+b, ho_e = ho@W_hoe^T+b  (fp32 outputs)
  GemmArgs gc{fr_bf, Wfre_bf, bfre_f, nullptr, fre_f, 0, nullptr};
  GemmArgs gd{ho_bf, Whoe_bf, bhoe_f, nullptr, hoe_f, 0, nullptr};
  gemm_k<<<dim3(4, 32, 2), blk, 0, stream>>>(gc, gd);

  // 5: attention scores over L+1 = 197 slots
  int nrows = BATCH * LP1;                      // 25216, divisible by 4
  scores_k<<<dim3(nrows / 4), blk, 0, stream>>>(flag, conv_feat_e, fre_f, hoe_f,
                                                Wa_f, ba_f, scores);

  // 6: softmax
  softmax_k<<<dim3(BATCH), blk, 0, stream>>>(scores, PI);

  // 7: visAtt + ho -> attout (bf16)
  visatt_k<<<dim3(BATCH), blk, 0, stream>>>(flag, conv_feat, fr_bf, ho_f, PI, attout);

  // 8: h = tanh(attout@W_h^T + b_h) -> d_out (dtype per flag)
  GemmArgs ge{attout, Wh_bf, bh_f, (uint16_t*)d_out, (float*)d_out, 2, flag};
  gemm_k<<<dim3(4, 32, 1), blk, 0, stream>>>(ge, ge);
}